// Round 7
// baseline (613.156 us; speedup 1.0000x reference)
//
#include <hip/hip_runtime.h>

typedef __bf16 bf16;
typedef bf16 bf16x4 __attribute__((ext_vector_type(4)));
typedef bf16 bf16x8 __attribute__((ext_vector_type(8)));
typedef float f32x4 __attribute__((ext_vector_type(4)));

#define B_  4
#define S_  2048
#define E_  1152
#define H_  12
#define D_  96
#define HD_ 1152      // H_*D_
#define M_  (B_*S_)   // 8192
#define BH_ (B_*H_)   // 48

__device__ __forceinline__ void gl2lds16(const void* g, void* l) {
    __builtin_amdgcn_global_load_lds((const __attribute__((address_space(1))) void*)g,
                                     (__attribute__((address_space(3))) void*)l, 16, 0, 0);
}

// ---------------------------------------------------------------- fused prep:
// [0,9216): cast logits fp32->bf16 ; [9216,9600): rope table ; [9600,14784): 4x W transpose
#define CAST_B_ 9216
#define TAB_B_  384
__global__ __launch_bounds__(256) void prep_k(const float* __restrict__ logits,
        bf16* __restrict__ Xbf, float2* __restrict__ ctab,
        const float* __restrict__ W0, const float* __restrict__ W1,
        const float* __restrict__ W2, const float* __restrict__ W3,
        bf16* __restrict__ T0, bf16* __restrict__ T1,
        bf16* __restrict__ T2, bf16* __restrict__ T3) {
    __shared__ float tsm[32][33];
    int bid = blockIdx.x, t = threadIdx.x;
    if (bid < CAST_B_) {
        size_t i = ((size_t)bid * 256 + t) * 4;
        float4 v = *(const float4*)(logits + i);
        bf16x4 o = { (bf16)v.x, (bf16)v.y, (bf16)v.z, (bf16)v.w };
        *(bf16x4*)(Xbf + i) = o;
    } else if (bid < CAST_B_ + TAB_B_) {
        int idx = (bid - CAST_B_) * 256 + t;
        int s = idx / 48, i = idx % 48;
        float theta = powf(10000.0f, -(float)(2 * i) / 96.0f);
        float ang = (float)s * theta;
        ctab[idx] = make_float2(cosf(ang), sinf(ang));
    } else {
        int tw = bid - (CAST_B_ + TAB_B_);
        int z = tw / 1296, rem = tw % 1296;
        const float* W; bf16* WT;
        switch (z) {
            case 0: W = W0; WT = T0; break;
            case 1: W = W1; WT = T1; break;
            case 2: W = W2; WT = T2; break;
            default: W = W3; WT = T3; break;
        }
        int bx = (rem % 36) * 32, by = (rem / 36) * 32;
        int tx = t & 31, ty = t >> 5;
        #pragma unroll
        for (int i = ty; i < 32; i += 8)
            tsm[i][tx] = W[(size_t)(by + i) * E_ + bx + tx];
        __syncthreads();
        #pragma unroll
        for (int i = ty; i < 32; i += 8)
            WT[(size_t)(bx + i) * E_ + by + tx] = (bf16)tsm[tx][i];
    }
}

// ---------------------------------------------------------------- 128x128 GEMM body, BK=64, XOR-swizzled LDS,
// register-prefetch pipeline: tile k+1 prefetched into VGPRs during tile k's
// MFMAs; ds_write at next iter -> barriers drain LDS-latency only, not HBM.
// mode: 0 = bf16 C, 1 = bf16 C + fused RoPE, 2 = write transposed VT, 3 = fp32 C
__device__ __forceinline__ void gemm128_body(const bf16* __restrict__ X,
                                             const bf16* __restrict__ WT,
                                             const float* __restrict__ bias,
                                             bf16* __restrict__ Cb,
                                             float* __restrict__ Cf,
                                             const float2* __restrict__ ctab,
                                             int K, int mode, int m0, int n0) {
    __shared__ bf16 As[128 * 64];
    __shared__ bf16 Bs[128 * 64];
    const int N = 1152;
    int t = threadIdx.x;
    int lane = t & 63, wave = t >> 6;
    int quad = lane >> 4, l16 = lane & 15;
    int wm = wave >> 1, wn = wave & 1;

    int srow = t >> 3;
    int scol = ((t & 7) ^ (srow & 7)) * 8;     // swizzled global col (elements)
    const bf16* ga = X  + (size_t)(m0 + srow) * K + scol;
    const bf16* gb = WT + (size_t)(n0 + srow) * K + scol;
    uint4* la = (uint4*)As + t;                // slot t, sections of 256 slots
    uint4* lb = (uint4*)Bs + t;
    size_t skip = (size_t)32 * K;

    uint4 ra[4], rb[4];
    #pragma unroll
    for (int i = 0; i < 4; ++i) {
        ra[i] = *(const uint4*)(ga + i * skip);
        rb[i] = *(const uint4*)(gb + i * skip);
    }

    f32x4 acc[4][4];
    #pragma unroll
    for (int u = 0; u < 4; ++u)
        #pragma unroll
        for (int v = 0; v < 4; ++v) acc[u][v] = (f32x4){0.f, 0.f, 0.f, 0.f};

    for (int k0 = 0; k0 < K; k0 += 64) {
        __syncthreads();                       // all waves done reading prev tile
        #pragma unroll
        for (int i = 0; i < 4; ++i) {          // vmcnt wait covers loads issued last iter
            la[i * 256] = ra[i];
            lb[i * 256] = rb[i];
        }
        __syncthreads();
        if (k0 + 64 < K) {                     // prefetch next tile, in flight during MFMAs
            #pragma unroll
            for (int i = 0; i < 4; ++i) {
                ra[i] = *(const uint4*)(ga + k0 + 64 + i * skip);
                rb[i] = *(const uint4*)(gb + k0 + 64 + i * skip);
            }
        }
        #pragma unroll
        for (int kk = 0; kk < 2; ++kk) {
            int xc = ((kk * 4 + quad) ^ (l16 & 7)) * 8;
            bf16x8 af[4], bfr[4];
            #pragma unroll
            for (int u = 0; u < 4; ++u)
                af[u] = *(const bf16x8*)(As + (wm * 64 + u * 16 + l16) * 64 + xc);
            #pragma unroll
            for (int v = 0; v < 4; ++v)
                bfr[v] = *(const bf16x8*)(Bs + (wn * 64 + v * 16 + l16) * 64 + xc);
            #pragma unroll
            for (int u = 0; u < 4; ++u)
                #pragma unroll
                for (int v = 0; v < 4; ++v)
                    acc[u][v] = __builtin_amdgcn_mfma_f32_16x16x32_bf16(af[u], bfr[v], acc[u][v], 0, 0, 0);
        }
    }

    int mrow = m0 + wm * 64, ncol = n0 + wn * 64;
    if (mode == 3) {
        #pragma unroll
        for (int v = 0; v < 4; ++v) {
            int n = ncol + v * 16 + l16;
            float bv = bias[n];
            #pragma unroll
            for (int u = 0; u < 4; ++u)
                #pragma unroll
                for (int r = 0; r < 4; ++r)
                    Cf[(size_t)(mrow + u * 16 + quad * 4 + r) * N + n] = acc[u][v][r] + bv;
        }
    } else if (mode == 1) {
        #pragma unroll
        for (int v = 0; v < 4; ++v) {
            int n = ncol + v * 16 + l16;
            float bv = bias[n];
            int i = (n % 96) >> 1;
            float sgn = (n & 1) ? 1.f : -1.f;
            #pragma unroll
            for (int u = 0; u < 4; ++u)
                #pragma unroll
                for (int r = 0; r < 4; ++r) {
                    int m = mrow + u * 16 + quad * 4 + r;
                    float x = acc[u][v][r] + bv;
                    float p = __shfl_xor(x, 1, 64);
                    float2 cs = ctab[(m & (S_ - 1)) * 48 + i];
                    Cb[(size_t)m * N + n] = (bf16)(x * cs.x + p * sgn * cs.y);
                }
        }
    } else if (mode == 2) {
        int bbase = (mrow >> 11) * H_;     // b*12 (block never straddles b)
        #pragma unroll
        for (int v = 0; v < 4; ++v) {
            int n = ncol + v * 16 + l16;
            int h = n / 96, d = n % 96;
            float bv = bias[n];
            bf16* vt = Cb + (size_t)((bbase + h) * 96 + d) * S_;
            #pragma unroll
            for (int u = 0; u < 4; ++u) {
                int s = (mrow + u * 16 + quad * 4) & (S_ - 1);
                bf16x4 val;
                #pragma unroll
                for (int r = 0; r < 4; ++r) val[r] = (bf16)(acc[u][v][r] + bv);
                *(bf16x4*)(vt + s) = val;   // b64 store, 4 consecutive s at fixed d
            }
        }
    } else {
        #pragma unroll
        for (int v = 0; v < 4; ++v) {
            int n = ncol + v * 16 + l16;
            float bv = bias[n];
            #pragma unroll
            for (int u = 0; u < 4; ++u)
                #pragma unroll
                for (int r = 0; r < 4; ++r)
                    Cb[(size_t)(mrow + u * 16 + quad * 4 + r) * N + n] = (bf16)(acc[u][v][r] + bv);
        }
    }
}

// fused QKV: grid (64, 27); zone = y/9 selects q/k/v. v-zone writes VT directly.
__global__ __launch_bounds__(256) void gemm_qkv_k(const bf16* __restrict__ X,
        const bf16* __restrict__ Wq, const bf16* __restrict__ Wk, const bf16* __restrict__ Wv,
        const float* __restrict__ bq, const float* __restrict__ bk, const float* __restrict__ bv,
        bf16* __restrict__ q, bf16* __restrict__ k, bf16* __restrict__ vt,
        const float2* __restrict__ ctab) {
    int zone = blockIdx.y / 9;
    int n0 = (blockIdx.y % 9) * 128;
    const bf16* W; const float* bias; bf16* C; int mode;
    if (zone == 0)      { W = Wq; bias = bq; C = q;  mode = 1; }
    else if (zone == 1) { W = Wk; bias = bk; C = k;  mode = 1; }
    else                { W = Wv; bias = bv; C = vt; mode = 2; }
    gemm128_body(X, W, bias, C, nullptr, ctab, E_, mode, blockIdx.x * 128, n0);
}

__global__ __launch_bounds__(256) void gemm_out_k(const bf16* __restrict__ X,
        const bf16* __restrict__ WT, const float* __restrict__ bias, float* __restrict__ Cf) {
    gemm128_body(X, WT, bias, nullptr, Cf, nullptr, HD_, 3, blockIdx.x * 128, blockIdx.y * 128);
}

// ---------------------------------------------------------------- flash attention v4
// Block = 128 q-rows of one (b,h); wave = 32 q (two 16-col B-fragment groups).
// S^T = K.Q^T (per-lane softmax, fixed shift); O^T = V^T.P^T.
__global__ __launch_bounds__(256) void flash4_k(const bf16* __restrict__ Q,
                                                const bf16* __restrict__ Kg,
                                                const bf16* __restrict__ VT,
                                                bf16* __restrict__ ctx) {
    __shared__ bf16 Ks[64 * 104];       // [s][d] pad 96->104
    __shared__ bf16 Vs[96 * 72];        // [d][s] pad 64->72
    __shared__ bf16 Ps[4][32][72];      // per-wave P[q][s]
    int t = threadIdx.x, lane = t & 63, wave = t >> 6;
    int quad = lane >> 4, l16 = lane & 15;
    int bh = blockIdx.x % BH_;
    int ch = (S_ / 128 - 1) - blockIdx.x / BH_;   // heavy chunks first
    int b = bh / H_, h = bh % H_;
    int q0 = ch * 128;
    int qw = q0 + wave * 32;
    int qg0 = qw + l16, qg1 = qw + 16 + l16;

    const char* KbaseB = (const char*)(Kg + (size_t)(b * S_) * HD_ + h * D_);
    const char* VbaseB = (const char*)(VT + (size_t)(bh * D_) * S_);

    int krow[4], koff[4], vrow[4], voff[4];
    #pragma unroll
    for (int i = 0; i < 4; ++i) {
        int c = i * 256 + t;
        krow[i] = c / 13; koff[i] = (c % 13) * 16;
        vrow[i] = c / 9;  int cc = c % 9; voff[i] = ((cc == 8) ? 7 : cc) * 16;
    }

    const bf16* qrow0 = Q + (size_t)(b * S_ + qw + l16) * HD_ + h * D_;
    const bf16* qrow1 = qrow0 + (size_t)16 * HD_;
    bf16x8 qf0[3], qf1[3];
    #pragma unroll
    for (int c = 0; c < 3; ++c) {
        qf0[c] = *(const bf16x8*)(qrow0 + c * 32 + quad * 8);
        qf1[c] = *(const bf16x8*)(qrow1 + c * 32 + quad * 8);
    }

    f32x4 o0[6], o1[6];
    #pragma unroll
    for (int u = 0; u < 6; ++u) { o0[u] = (f32x4){0.f,0.f,0.f,0.f}; o1[u] = (f32x4){0.f,0.f,0.f,0.f}; }
    float ls0 = 0.f, ls1 = 0.f;
    const float K2 = 0.10206207261596575f * 1.4426950408889634f;  // scale*log2(e)
    int nk = q0 + 128;

    for (int kb = 0; kb < nk; kb += 64) {
        __syncthreads();
        const char* kg = KbaseB + (size_t)kb * (HD_ * 2);
        #pragma unroll
        for (int i = 0; i < 3; ++i)
            gl2lds16(kg + (size_t)krow[i] * (HD_ * 2) + koff[i], (char*)Ks + i * 4096 + t * 16);
        if (t < 64)
            gl2lds16(kg + (size_t)krow[3] * (HD_ * 2) + koff[3], (char*)Ks + 12288 + t * 16);
        #pragma unroll
        for (int i = 0; i < 4; ++i)
            if (i < 3 || t < 96)
                gl2lds16(VbaseB + (size_t)vrow[i] * (S_ * 2) + (size_t)kb * 2 + voff[i],
                         (char*)Vs + i * 4096 + t * 16);
        __syncthreads();

        f32x4 s0[4], s1[4];
        #pragma unroll
        for (int u = 0; u < 4; ++u) { s0[u] = (f32x4){0.f,0.f,0.f,0.f}; s1[u] = (f32x4){0.f,0.f,0.f,0.f}; }
        #pragma unroll
        for (int c = 0; c < 3; ++c)
            #pragma unroll
            for (int u = 0; u < 4; ++u) {
                bf16x8 kf = *(const bf16x8*)(Ks + (u * 16 + l16) * 104 + c * 32 + quad * 8);
                s0[u] = __builtin_amdgcn_mfma_f32_16x16x32_bf16(kf, qf0[c], s0[u], 0, 0, 0);
                s1[u] = __builtin_amdgcn_mfma_f32_16x16x32_bf16(kf, qf1[c], s1[u], 0, 0, 0);
            }

        #pragma unroll
        for (int u = 0; u < 4; ++u) {
            bf16x4 pv0, pv1;
            #pragma unroll
            for (int r = 0; r < 4; ++r) {
                int sidx = kb + u * 16 + quad * 4 + r;
                float e0 = __builtin_exp2f(s0[u][r] * K2);
                float e1 = __builtin_exp2f(s1[u][r] * K2);
                e0 = (sidx <= qg0) ? e0 : 0.f;
                e1 = (sidx <= qg1) ? e1 : 0.f;
                ls0 += e0; ls1 += e1;
                pv0[r] = (bf16)e0; pv1[r] = (bf16)e1;
            }
            *(bf16x4*)(&Ps[wave][l16][u * 16 + quad * 4])      = pv0;
            *(bf16x4*)(&Ps[wave][16 + l16][u * 16 + quad * 4]) = pv1;
        }
        asm volatile("s_waitcnt lgkmcnt(0)" ::: "memory");

        bf16x8 p00 = *(const bf16x8*)(&Ps[wave][l16][quad * 8]);
        bf16x8 p01 = *(const bf16x8*)(&Ps[wave][l16][32 + quad * 8]);
        bf16x8 p10 = *(const bf16x8*)(&Ps[wave][16 + l16][quad * 8]);
        bf16x8 p11 = *(const bf16x8*)(&Ps[wave][16 + l16][32 + quad * 8]);
        #pragma unroll
        for (int u = 0; u < 6; ++u) {
            bf16x8 v0 = *(const bf16x8*)(Vs + (u * 16 + l16) * 72 + quad * 8);
            o0[u] = __builtin_amdgcn_mfma_f32_16x16x32_bf16(v0, p00, o0[u], 0, 0, 0);
            o1[u] = __builtin_amdgcn_mfma_f32_16x16x32_bf16(v0, p10, o1[u], 0, 0, 0);
            bf16x8 v1 = *(const bf16x8*)(Vs + (u * 16 + l16) * 72 + 32 + quad * 8);
            o0[u] = __builtin_amdgcn_mfma_f32_16x16x32_bf16(v1, p01, o0[u], 0, 0, 0);
            o1[u] = __builtin_amdgcn_mfma_f32_16x16x32_bf16(v1, p11, o1[u], 0, 0, 0);
        }
    }

    ls0 += __shfl_xor(ls0, 16, 64); ls0 += __shfl_xor(ls0, 32, 64);
    ls1 += __shfl_xor(ls1, 16, 64); ls1 += __shfl_xor(ls1, 32, 64);
    float inv0 = 1.0f / ls0, inv1 = 1.0f / ls1;

    bf16* crow0 = ctx + (size_t)(b * S_ + qw + l16) * HD_ + h * D_;
    bf16* crow1 = crow0 + (size_t)16 * HD_;
    #pragma unroll
    for (int u = 0; u < 6; ++u) {
        bf16x4 a, c;
        #pragma unroll
        for (int r = 0; r < 4; ++r) { a[r] = (bf16)(o0[u][r] * inv0); c[r] = (bf16)(o1[u][r] * inv1); }
        *(bf16x4*)(crow0 + u * 16 + quad * 4) = a;
        *(bf16x4*)(crow1 + u * 16 + quad * 4) = c;
    }
}

// ---------------------------------------------------------------- launch
extern "C" void kernel_launch(void* const* d_in, const int* in_sizes, int n_in,
                              void* d_out, int out_size, void* d_ws, size_t ws_size,
                              hipStream_t stream) {
    const float* logits = (const float*)d_in[0];
    const float* Wq = (const float*)d_in[1];
    const float* bq = (const float*)d_in[2];
    const float* Wk = (const float*)d_in[3];
    const float* bk = (const float*)d_in[4];
    const float* Wv = (const float*)d_in[5];
    const float* bv = (const float*)d_in[6];
    const float* Wo = (const float*)d_in[7];
    const float* bo = (const float*)d_in[8];
    float* out = (float*)d_out;

    char* ws = (char*)d_ws;
    size_t off = 0;
    auto alloc = [&](size_t bytes) { char* p = ws + off; off += (bytes + 255) & ~(size_t)255; return p; };
    bf16* Xbf = (bf16*)alloc((size_t)M_ * E_ * 2);
    bf16* WqT = (bf16*)alloc((size_t)E_ * HD_ * 2);
    bf16* WkT = (bf16*)alloc((size_t)E_ * HD_ * 2);
    bf16* WvT = (bf16*)alloc((size_t)E_ * HD_ * 2);
    bf16* WoT = (bf16*)alloc((size_t)HD_ * E_ * 2);
    bf16* qb  = (bf16*)alloc((size_t)M_ * HD_ * 2);
    bf16* kb  = (bf16*)alloc((size_t)M_ * HD_ * 2);
    bf16* VT  = (bf16*)alloc((size_t)M_ * HD_ * 2);
    float2* ctab = (float2*)alloc((size_t)S_ * 48 * 8);
    bf16* ctx = Xbf;  // reuse: logits-bf16 dead after QKV GEMMs

    hipLaunchKernelGGL(prep_k, dim3(CAST_B_ + TAB_B_ + 4 * 1296), dim3(256), 0, stream,
                       logits, Xbf, ctab, Wq, Wk, Wv, Wo, WqT, WkT, WvT, WoT);
    hipLaunchKernelGGL(gemm_qkv_k, dim3(M_ / 128, 27), dim3(256), 0, stream,
                       Xbf, WqT, WkT, WvT, bq, bk, bv, qb, kb, VT, ctab);
    hipLaunchKernelGGL(flash4_k, dim3(BH_ * (S_ / 128)), dim3(256), 0, stream, qb, kb, VT, ctx);
    hipLaunchKernelGGL(gemm_out_k, dim3(M_ / 128, 1152 / 128), dim3(256), 0, stream, ctx, WoT, bo, out);
}

// Round 8
// 318.619 us; speedup vs baseline: 1.9244x; 1.9244x over previous
//
#include <hip/hip_runtime.h>

typedef __bf16 bf16;
typedef bf16 bf16x4 __attribute__((ext_vector_type(4)));
typedef bf16 bf16x8 __attribute__((ext_vector_type(8)));
typedef float f32x4 __attribute__((ext_vector_type(4)));

#define B_  4
#define S_  2048
#define E_  1152
#define H_  12
#define D_  96
#define HD_ 1152      // H_*D_
#define M_  (B_*S_)   // 8192
#define BH_ (B_*H_)   // 48

__device__ __forceinline__ void gl2lds16(const void* g, void* l) {
    __builtin_amdgcn_global_load_lds((const __attribute__((address_space(1))) void*)g,
                                     (__attribute__((address_space(3))) void*)l, 16, 0, 0);
}

// ---------------------------------------------------------------- fused prep:
// [0,9216): cast logits fp32->bf16 ; [9216,9600): rope table ; [9600,14784): 4x W transpose
#define CAST_B_ 9216
#define TAB_B_  384
__global__ __launch_bounds__(256) void prep_k(const float* __restrict__ logits,
        bf16* __restrict__ Xbf, float2* __restrict__ ctab,
        const float* __restrict__ W0, const float* __restrict__ W1,
        const float* __restrict__ W2, const float* __restrict__ W3,
        bf16* __restrict__ T0, bf16* __restrict__ T1,
        bf16* __restrict__ T2, bf16* __restrict__ T3) {
    __shared__ float tsm[32][33];
    int bid = blockIdx.x, t = threadIdx.x;
    if (bid < CAST_B_) {
        size_t i = ((size_t)bid * 256 + t) * 4;
        float4 v = *(const float4*)(logits + i);
        bf16x4 o = { (bf16)v.x, (bf16)v.y, (bf16)v.z, (bf16)v.w };
        *(bf16x4*)(Xbf + i) = o;
    } else if (bid < CAST_B_ + TAB_B_) {
        int idx = (bid - CAST_B_) * 256 + t;
        int s = idx / 48, i = idx % 48;
        float theta = powf(10000.0f, -(float)(2 * i) / 96.0f);
        float ang = (float)s * theta;
        ctab[idx] = make_float2(cosf(ang), sinf(ang));
    } else {
        int tw = bid - (CAST_B_ + TAB_B_);
        int z = tw / 1296, rem = tw % 1296;
        const float* W; bf16* WT;
        switch (z) {
            case 0: W = W0; WT = T0; break;
            case 1: W = W1; WT = T1; break;
            case 2: W = W2; WT = T2; break;
            default: W = W3; WT = T3; break;
        }
        int bx = (rem % 36) * 32, by = (rem / 36) * 32;
        int tx = t & 31, ty = t >> 5;
        #pragma unroll
        for (int i = ty; i < 32; i += 8)
            tsm[i][tx] = W[(size_t)(by + i) * E_ + bx + tx];
        __syncthreads();
        #pragma unroll
        for (int i = ty; i < 32; i += 8)
            WT[(size_t)(bx + i) * E_ + by + tx] = (bf16)tsm[tx][i];
    }
}

// ---------------------------------------------------------------- 128x128 GEMM body, BK=64, XOR-swizzled LDS
// (round-6 structure: global_load_lds staging; reg-prefetch variant spilled to scratch -> reverted)
// mode: 0 = bf16 C, 1 = bf16 C + fused RoPE, 2 = write transposed VT, 3 = fp32 C
__device__ __forceinline__ void gemm128_body(const bf16* __restrict__ X,
                                             const bf16* __restrict__ WT,
                                             const float* __restrict__ bias,
                                             bf16* __restrict__ Cb,
                                             float* __restrict__ Cf,
                                             const float2* __restrict__ ctab,
                                             int K, int mode, int m0, int n0) {
    __shared__ bf16 As[128 * 64];
    __shared__ bf16 Bs[128 * 64];
    const int N = 1152;
    int t = threadIdx.x;
    int lane = t & 63, wave = t >> 6;
    int quad = lane >> 4, l16 = lane & 15;
    int wm = wave >> 1, wn = wave & 1;

    int srow = t >> 3;
    int scol = ((t & 7) ^ (srow & 7)) * 8;
    const bf16* ga = X  + (size_t)(m0 + srow) * K + scol;
    const bf16* gb = WT + (size_t)(n0 + srow) * K + scol;
    bf16* la = As + t * 8;
    bf16* lb = Bs + t * 8;
    size_t skip = (size_t)32 * K;

    f32x4 acc[4][4];
    #pragma unroll
    for (int u = 0; u < 4; ++u)
        #pragma unroll
        for (int v = 0; v < 4; ++v) acc[u][v] = (f32x4){0.f, 0.f, 0.f, 0.f};

    for (int k0 = 0; k0 < K; k0 += 64) {
        __syncthreads();
        #pragma unroll
        for (int i = 0; i < 4; ++i) {
            gl2lds16(ga + k0 + i * skip, la + i * 2048);
            gl2lds16(gb + k0 + i * skip, lb + i * 2048);
        }
        __syncthreads();
        #pragma unroll
        for (int kk = 0; kk < 2; ++kk) {
            int xc = ((kk * 4 + quad) ^ (l16 & 7)) * 8;
            bf16x8 af[4], bfr[4];
            #pragma unroll
            for (int u = 0; u < 4; ++u)
                af[u] = *(const bf16x8*)(As + (wm * 64 + u * 16 + l16) * 64 + xc);
            #pragma unroll
            for (int v = 0; v < 4; ++v)
                bfr[v] = *(const bf16x8*)(Bs + (wn * 64 + v * 16 + l16) * 64 + xc);
            #pragma unroll
            for (int u = 0; u < 4; ++u)
                #pragma unroll
                for (int v = 0; v < 4; ++v)
                    acc[u][v] = __builtin_amdgcn_mfma_f32_16x16x32_bf16(af[u], bfr[v], acc[u][v], 0, 0, 0);
        }
    }

    int mrow = m0 + wm * 64, ncol = n0 + wn * 64;
    if (mode == 3) {
        #pragma unroll
        for (int v = 0; v < 4; ++v) {
            int n = ncol + v * 16 + l16;
            float bv = bias[n];
            #pragma unroll
            for (int u = 0; u < 4; ++u)
                #pragma unroll
                for (int r = 0; r < 4; ++r)
                    Cf[(size_t)(mrow + u * 16 + quad * 4 + r) * N + n] = acc[u][v][r] + bv;
        }
    } else if (mode == 1) {
        #pragma unroll
        for (int v = 0; v < 4; ++v) {
            int n = ncol + v * 16 + l16;
            float bv = bias[n];
            int i = (n % 96) >> 1;
            float sgn = (n & 1) ? 1.f : -1.f;
            #pragma unroll
            for (int u = 0; u < 4; ++u)
                #pragma unroll
                for (int r = 0; r < 4; ++r) {
                    int m = mrow + u * 16 + quad * 4 + r;
                    float x = acc[u][v][r] + bv;
                    float p = __shfl_xor(x, 1, 64);
                    float2 cs = ctab[(m & (S_ - 1)) * 48 + i];
                    Cb[(size_t)m * N + n] = (bf16)(x * cs.x + p * sgn * cs.y);
                }
        }
    } else if (mode == 2) {
        int bbase = (mrow >> 11) * H_;     // b*12 (block never straddles b)
        #pragma unroll
        for (int v = 0; v < 4; ++v) {
            int n = ncol + v * 16 + l16;
            int h = n / 96, d = n % 96;
            float bv = bias[n];
            bf16* vt = Cb + (size_t)((bbase + h) * 96 + d) * S_;
            #pragma unroll
            for (int u = 0; u < 4; ++u) {
                int s = (mrow + u * 16 + quad * 4) & (S_ - 1);
                bf16x4 val;
                #pragma unroll
                for (int r = 0; r < 4; ++r) val[r] = (bf16)(acc[u][v][r] + bv);
                *(bf16x4*)(vt + s) = val;   // b64 store, 4 consecutive s at fixed d
            }
        }
    } else {
        #pragma unroll
        for (int v = 0; v < 4; ++v) {
            int n = ncol + v * 16 + l16;
            float bv = bias[n];
            #pragma unroll
            for (int u = 0; u < 4; ++u)
                #pragma unroll
                for (int r = 0; r < 4; ++r)
                    Cb[(size_t)(mrow + u * 16 + quad * 4 + r) * N + n] = (bf16)(acc[u][v][r] + bv);
        }
    }
}

// fused QKV: grid (64, 27); zone = y/9 selects q/k/v. v-zone writes VT directly.
__global__ __launch_bounds__(256) void gemm_qkv_k(const bf16* __restrict__ X,
        const bf16* __restrict__ Wq, const bf16* __restrict__ Wk, const bf16* __restrict__ Wv,
        const float* __restrict__ bq, const float* __restrict__ bk, const float* __restrict__ bv,
        bf16* __restrict__ q, bf16* __restrict__ k, bf16* __restrict__ vt,
        const float2* __restrict__ ctab) {
    int zone = blockIdx.y / 9;
    int n0 = (blockIdx.y % 9) * 128;
    const bf16* W; const float* bias; bf16* C; int mode;
    if (zone == 0)      { W = Wq; bias = bq; C = q;  mode = 1; }
    else if (zone == 1) { W = Wk; bias = bk; C = k;  mode = 1; }
    else                { W = Wv; bias = bv; C = vt; mode = 2; }
    gemm128_body(X, W, bias, C, nullptr, ctab, E_, mode, blockIdx.x * 128, n0);
}

__global__ __launch_bounds__(256) void gemm_out_k(const bf16* __restrict__ X,
        const bf16* __restrict__ WT, const float* __restrict__ bias, float* __restrict__ Cf) {
    gemm128_body(X, WT, bias, nullptr, Cf, nullptr, HD_, 3, blockIdx.x * 128, blockIdx.y * 128);
}

// ---------------------------------------------------------------- flash attention v5
// Block = 128 q-rows of one (b,h); wave = 32 q (two 16-col B-fragment groups).
// S^T = K.Q^T (per-lane softmax, fixed shift); O^T = V^T.P^T.
// New: (a) wave-uniform mask-free fast path; (b) skip all-masked tiles;
// (c) softmax denominator via constant-1 V-row (MFMA computes row-sum of P).
__global__ __launch_bounds__(256) void flash5_k(const bf16* __restrict__ Q,
                                                const bf16* __restrict__ Kg,
                                                const bf16* __restrict__ VT,
                                                bf16* __restrict__ ctx) {
    __shared__ bf16 Ks[64 * 104];       // [s][d] pad 96->104
    __shared__ bf16 Vs[112 * 72];       // [d][s] pad 64->72; rows 96..111: ones-row block
    __shared__ bf16 Ps[4][32][72];      // per-wave P[q][s]
    int t = threadIdx.x, lane = t & 63, wave = t >> 6;
    int quad = lane >> 4, l16 = lane & 15;
    int bh = blockIdx.x % BH_;
    int ch = (S_ / 128 - 1) - blockIdx.x / BH_;   // heavy chunks first
    int b = bh / H_, h = bh % H_;
    int q0 = ch * 128;
    int qw = q0 + wave * 32;
    int qg0 = qw + l16, qg1 = qw + 16 + l16;

    // ones-row block: row 96 = 1.0 (cols 0..71), rows 97..111 = 0
    for (int j = t; j < 16 * 72; j += 256)
        Vs[96 * 72 + j] = (j < 72) ? (bf16)1.0f : (bf16)0.0f;

    const char* KbaseB = (const char*)(Kg + (size_t)(b * S_) * HD_ + h * D_);
    const char* VbaseB = (const char*)(VT + (size_t)(bh * D_) * S_);

    int krow[4], koff[4], vrow[4], voff[4];
    #pragma unroll
    for (int i = 0; i < 4; ++i) {
        int c = i * 256 + t;
        krow[i] = c / 13; koff[i] = (c % 13) * 16;
        vrow[i] = c / 9;  int cc = c % 9; voff[i] = ((cc == 8) ? 7 : cc) * 16;
    }

    const bf16* qrow0 = Q + (size_t)(b * S_ + qw + l16) * HD_ + h * D_;
    const bf16* qrow1 = qrow0 + (size_t)16 * HD_;
    bf16x8 qf0[3], qf1[3];
    #pragma unroll
    for (int c = 0; c < 3; ++c) {
        qf0[c] = *(const bf16x8*)(qrow0 + c * 32 + quad * 8);
        qf1[c] = *(const bf16x8*)(qrow1 + c * 32 + quad * 8);
    }

    f32x4 o0[7], o1[7];   // [6] = ones-row accumulator (row 96 = sum of P)
    #pragma unroll
    for (int u = 0; u < 7; ++u) { o0[u] = (f32x4){0.f,0.f,0.f,0.f}; o1[u] = (f32x4){0.f,0.f,0.f,0.f}; }
    const float K2 = 0.10206207261596575f * 1.4426950408889634f;  // scale*log2(e)
    int nk = q0 + 128;

    for (int kb = 0; kb < nk; kb += 64) {
        __syncthreads();
        const char* kg = KbaseB + (size_t)kb * (HD_ * 2);
        #pragma unroll
        for (int i = 0; i < 3; ++i)
            gl2lds16(kg + (size_t)krow[i] * (HD_ * 2) + koff[i], (char*)Ks + i * 4096 + t * 16);
        if (t < 64)
            gl2lds16(kg + (size_t)krow[3] * (HD_ * 2) + koff[3], (char*)Ks + 12288 + t * 16);
        #pragma unroll
        for (int i = 0; i < 4; ++i)
            if (i < 3 || t < 96)
                gl2lds16(VbaseB + (size_t)vrow[i] * (S_ * 2) + (size_t)kb * 2 + voff[i],
                         (char*)Vs + i * 4096 + t * 16);
        __syncthreads();

        if (kb >= qw + 32) continue;      // all-masked for this wave (still hits barriers)

        f32x4 s0[4], s1[4];
        #pragma unroll
        for (int u = 0; u < 4; ++u) { s0[u] = (f32x4){0.f,0.f,0.f,0.f}; s1[u] = (f32x4){0.f,0.f,0.f,0.f}; }
        #pragma unroll
        for (int c = 0; c < 3; ++c)
            #pragma unroll
            for (int u = 0; u < 4; ++u) {
                bf16x8 kf = *(const bf16x8*)(Ks + (u * 16 + l16) * 104 + c * 32 + quad * 8);
                s0[u] = __builtin_amdgcn_mfma_f32_16x16x32_bf16(kf, qf0[c], s0[u], 0, 0, 0);
                s1[u] = __builtin_amdgcn_mfma_f32_16x16x32_bf16(kf, qf1[c], s1[u], 0, 0, 0);
            }

        if (kb + 64 <= qw) {              // fully unmasked for both q-groups
            #pragma unroll
            for (int u = 0; u < 4; ++u) {
                bf16x4 pv0, pv1;
                #pragma unroll
                for (int r = 0; r < 4; ++r) {
                    pv0[r] = (bf16)__builtin_exp2f(s0[u][r] * K2);
                    pv1[r] = (bf16)__builtin_exp2f(s1[u][r] * K2);
                }
                *(bf16x4*)(&Ps[wave][l16][u * 16 + quad * 4])      = pv0;
                *(bf16x4*)(&Ps[wave][16 + l16][u * 16 + quad * 4]) = pv1;
            }
        } else {                          // diagonal tile: causal masks
            #pragma unroll
            for (int u = 0; u < 4; ++u) {
                bf16x4 pv0, pv1;
                #pragma unroll
                for (int r = 0; r < 4; ++r) {
                    int sidx = kb + u * 16 + quad * 4 + r;
                    float e0 = __builtin_exp2f(s0[u][r] * K2);
                    float e1 = __builtin_exp2f(s1[u][r] * K2);
                    pv0[r] = (bf16)((sidx <= qg0) ? e0 : 0.f);
                    pv1[r] = (bf16)((sidx <= qg1) ? e1 : 0.f);
                }
                *(bf16x4*)(&Ps[wave][l16][u * 16 + quad * 4])      = pv0;
                *(bf16x4*)(&Ps[wave][16 + l16][u * 16 + quad * 4]) = pv1;
            }
        }
        asm volatile("s_waitcnt lgkmcnt(0)" ::: "memory");

        bf16x8 p00 = *(const bf16x8*)(&Ps[wave][l16][quad * 8]);
        bf16x8 p01 = *(const bf16x8*)(&Ps[wave][l16][32 + quad * 8]);
        bf16x8 p10 = *(const bf16x8*)(&Ps[wave][16 + l16][quad * 8]);
        bf16x8 p11 = *(const bf16x8*)(&Ps[wave][16 + l16][32 + quad * 8]);
        #pragma unroll
        for (int u = 0; u < 7; ++u) {
            bf16x8 v0 = *(const bf16x8*)(Vs + (u * 16 + l16) * 72 + quad * 8);
            o0[u] = __builtin_amdgcn_mfma_f32_16x16x32_bf16(v0, p00, o0[u], 0, 0, 0);
            o1[u] = __builtin_amdgcn_mfma_f32_16x16x32_bf16(v0, p10, o1[u], 0, 0, 0);
            bf16x8 v1 = *(const bf16x8*)(Vs + (u * 16 + l16) * 72 + 32 + quad * 8);
            o0[u] = __builtin_amdgcn_mfma_f32_16x16x32_bf16(v1, p01, o0[u], 0, 0, 0);
            o1[u] = __builtin_amdgcn_mfma_f32_16x16x32_bf16(v1, p11, o1[u], 0, 0, 0);
        }
    }

    // denominator lives in lane (quad=0, l16), reg o[6][0] (row 96) -> broadcast
    float inv0 = 1.0f / __shfl(o0[6][0], l16, 64);
    float inv1 = 1.0f / __shfl(o1[6][0], l16, 64);

    bf16* crow0 = ctx + (size_t)(b * S_ + qw + l16) * HD_ + h * D_;
    bf16* crow1 = crow0 + (size_t)16 * HD_;
    #pragma unroll
    for (int u = 0; u < 6; ++u) {
        bf16x4 a, c;
        #pragma unroll
        for (int r = 0; r < 4; ++r) { a[r] = (bf16)(o0[u][r] * inv0); c[r] = (bf16)(o1[u][r] * inv1); }
        *(bf16x4*)(crow0 + u * 16 + quad * 4) = a;
        *(bf16x4*)(crow1 + u * 16 + quad * 4) = c;
    }
}

// ---------------------------------------------------------------- launch
extern "C" void kernel_launch(void* const* d_in, const int* in_sizes, int n_in,
                              void* d_out, int out_size, void* d_ws, size_t ws_size,
                              hipStream_t stream) {
    const float* logits = (const float*)d_in[0];
    const float* Wq = (const float*)d_in[1];
    const float* bq = (const float*)d_in[2];
    const float* Wk = (const float*)d_in[3];
    const float* bk = (const float*)d_in[4];
    const float* Wv = (const float*)d_in[5];
    const float* bv = (const float*)d_in[6];
    const float* Wo = (const float*)d_in[7];
    const float* bo = (const float*)d_in[8];
    float* out = (float*)d_out;

    char* ws = (char*)d_ws;
    size_t off = 0;
    auto alloc = [&](size_t bytes) { char* p = ws + off; off += (bytes + 255) & ~(size_t)255; return p; };
    bf16* Xbf = (bf16*)alloc((size_t)M_ * E_ * 2);
    bf16* WqT = (bf16*)alloc((size_t)E_ * HD_ * 2);
    bf16* WkT = (bf16*)alloc((size_t)E_ * HD_ * 2);
    bf16* WvT = (bf16*)alloc((size_t)E_ * HD_ * 2);
    bf16* WoT = (bf16*)alloc((size_t)HD_ * E_ * 2);
    bf16* qb  = (bf16*)alloc((size_t)M_ * HD_ * 2);
    bf16* kb  = (bf16*)alloc((size_t)M_ * HD_ * 2);
    bf16* VT  = (bf16*)alloc((size_t)M_ * HD_ * 2);
    float2* ctab = (float2*)alloc((size_t)S_ * 48 * 8);
    bf16* ctx = Xbf;  // reuse: logits-bf16 dead after QKV GEMMs

    hipLaunchKernelGGL(prep_k, dim3(CAST_B_ + TAB_B_ + 4 * 1296), dim3(256), 0, stream,
                       logits, Xbf, ctab, Wq, Wk, Wv, Wo, WqT, WkT, WvT, WoT);
    hipLaunchKernelGGL(gemm_qkv_k, dim3(M_ / 128, 27), dim3(256), 0, stream,
                       Xbf, WqT, WkT, WvT, bq, bk, bv, qb, kb, VT, ctab);
    hipLaunchKernelGGL(flash5_k, dim3(BH_ * (S_ / 128)), dim3(256), 0, stream, qb, kb, VT, ctx);
    hipLaunchKernelGGL(gemm_out_k, dim3(M_ / 128, 1152 / 128), dim3(256), 0, stream, ctx, WoT, bo, out);
}